// Round 2
// baseline (472.449 us; speedup 1.0000x reference)
//
#include <hip/hip_runtime.h>
#include <hip/hip_bf16.h>

#define NRELS 4
#define MAXDEG 10
#define NBUCK 11
#define POOL_CHUNKS 8

typedef __attribute__((ext_vector_type(8))) short s16x8;
typedef __attribute__((ext_vector_type(4))) float f32x4;
typedef __attribute__((ext_vector_type(8))) unsigned short u16x8;

__device__ inline unsigned short f2b(float f) {
  __hip_bfloat16 h = __float2bfloat16(f);
  return *reinterpret_cast<unsigned short*>(&h);
}
__device__ inline float b2f(unsigned short u) {
  union { unsigned int i; float f; } v;
  v.i = ((unsigned int)u) << 16;
  return v.f;
}
__device__ inline float blo(unsigned int v) {
  union { unsigned int i; float f; } x;
  x.i = v << 16;
  return x.f;
}
__device__ inline float bhi(unsigned int v) {
  union { unsigned int i; float f; } x;
  x.i = v & 0xffff0000u;
  return x.f;
}

typedef __attribute__((address_space(3))) unsigned int lds_uint;
typedef __attribute__((address_space(1))) const unsigned int glob_uint;
__device__ __forceinline__ void gld_lds16(const void* g, void* l) {
  __builtin_amdgcn_global_load_lds((glob_uint*)g, (lds_uint*)l, 16, 0, 0);
}

// ================================================================ CSR build
__global__ __launch_bounds__(512) void coarse_count_scan(
    const int* __restrict__ dst, int* __restrict__ bhist, int* __restrict__ boff,
    int* __restrict__ bcur, int* __restrict__ done, int* __restrict__ perm, int permCap,
    int NB, int E, int nblocks) {
  __shared__ int lh[512];
  __shared__ int lastf;
  int t = threadIdx.x;
  lh[t] = 0;
  __syncthreads();
  for (int i = blockIdx.x * 512 + t; i < permCap; i += nblocks * 512) perm[i] = -1;
  int base = blockIdx.x * 4096;
  int lim = E - base;
  if (lim > 4096) lim = 4096;
  for (int i = t; i < lim; i += 512) atomicAdd(&lh[dst[base + i] >> 7], 1);
  __syncthreads();
  if (lh[t]) atomicAdd(&bhist[t], lh[t]);
  __threadfence();
  __syncthreads();
  if (t == 0) lastf = (atomicAdd(done, 1) == nblocks - 1) ? 1 : 0;
  __syncthreads();
  if (!lastf) return;
  int v = (t < NB) ? atomicAdd(&bhist[t], 0) : 0;
  lh[t] = v;
  __syncthreads();
  for (int o = 1; o < 512; o <<= 1) {
    int x = (t >= o) ? lh[t - o] : 0;
    __syncthreads();
    lh[t] += x;
    __syncthreads();
  }
  if (t < NB) {
    int st = lh[t] - v;
    boff[t] = st;
    bcur[t] = st;
  }
  if (t == 0) boff[NB] = E;
}

__global__ __launch_bounds__(512) void coarse_scatter(
    const int* __restrict__ src, const int* __restrict__ dst, const int* __restrict__ rel,
    int* __restrict__ bcur, uint2* __restrict__ ebuf, int E) {
  __shared__ int lhist[512];
  __shared__ int lstart[512];
  __shared__ int lcur[512];
  __shared__ int gbase[512];
  __shared__ uint2 stage[4096];
  int t = threadIdx.x;
  lhist[t] = 0;
  __syncthreads();
  int base = blockIdx.x * 4096;
  int lim = E - base;
  if (lim > 4096) lim = 4096;
  for (int i = t; i < lim; i += 512) atomicAdd(&lhist[dst[base + i] >> 7], 1);
  __syncthreads();
  int myc = lhist[t];
  lstart[t] = myc;
  __syncthreads();
  for (int o = 1; o < 512; o <<= 1) {
    int x = (t >= o) ? lstart[t - o] : 0;
    __syncthreads();
    lstart[t] += x;
    __syncthreads();
  }
  int incl = lstart[t];
  __syncthreads();
  lstart[t] = incl - myc;
  lcur[t] = 0;
  if (myc > 0) gbase[t] = atomicAdd(&bcur[t], myc);
  __syncthreads();
  for (int i = t; i < lim; i += 512) {
    int e = base + i;
    int d = dst[e];
    int b = d >> 7;
    int slot = lstart[b] + atomicAdd(&lcur[b], 1);
    stage[slot] = make_uint2((unsigned)(d * 4 + rel[e]), (unsigned)src[e]);
  }
  __syncthreads();
  for (int i = t; i < lim; i += 512) {
    uint2 val = stage[i];
    int b = (int)(val.x >> 9);
    ebuf[gbase[b] + (i - lstart[b])] = val;
  }
}

__global__ __launch_bounds__(512) void fine_place(
    const uint2* __restrict__ ebuf, const int* __restrict__ boff, int* __restrict__ cnt,
    int* __restrict__ seg_start, float* __restrict__ inv, int* __restrict__ deg,
    int* __restrict__ bucket, int* __restrict__ hist, int* __restrict__ csr, int NSEG) {
  __shared__ int lh[512];
  __shared__ int sc[512];
  __shared__ int lcur[512];
  __shared__ int lbh[16];
  int t = threadIdx.x;
  int b = blockIdx.x;
  lh[t] = 0;
  if (t < 16) lbh[t] = 0;
  __syncthreads();
  int s = boff[b], e = boff[b + 1];
  for (int i = s + t; i < e; i += 512) atomicAdd(&lh[ebuf[i].x & 511], 1);
  __syncthreads();
  int v = lh[t];
  sc[t] = v;
  __syncthreads();
  for (int o = 1; o < 512; o <<= 1) {
    int x = (t >= o) ? sc[t - o] : 0;
    __syncthreads();
    sc[t] += x;
    __syncthreads();
  }
  int gseg = b * 512 + t;
  int mystart = s + sc[t] - v;
  lcur[t] = mystart;
  if (gseg < NSEG) {
    cnt[gseg] = v;
    seg_start[gseg] = mystart;
    inv[gseg] = 1.0f / (float)(v > 1 ? v : 1);
    if ((t & 3) == 0) {
      int d = sc[t + 3] - sc[t] + v;
      int n = gseg >> 2;
      deg[n] = d;
      int bk = d < MAXDEG ? d : MAXDEG;
      bucket[n] = bk;
      atomicAdd(&lbh[bk], 1);
    }
  }
  __syncthreads();
  if (t < NBUCK && lbh[t]) atomicAdd(&hist[t], lbh[t]);
  for (int i = s + t; i < e; i += 512) {
    uint2 vv = ebuf[i];
    int pos = atomicAdd(&lcur[vv.x & 511], 1);
    csr[pos] = (int)vv.y;
  }
}

__global__ void build_perm(const int* __restrict__ bucket, const int* __restrict__ hist,
                           int* __restrict__ fill, int* __restrict__ perm, int N) {
  __shared__ int soff[NBUCK];
  if (threadIdx.x == 0) {
    int acc = 0;
    for (int b = 0; b < NBUCK; b++) {
      soff[b] = acc;
      acc += ((hist[b] + 63) >> 6) << 6;
    }
  }
  __syncthreads();
  int n = blockIdx.x * 256 + threadIdx.x;
  int b = (n < N) ? bucket[n] : -1;
  int lane = threadIdx.x & 63;
  for (int bb = 0; bb < NBUCK; bb++) {
    unsigned long long m = __ballot(b == bb);
    if (m == 0ULL) continue;
    int leader = __ffsll(m) - 1;
    int base = 0;
    if (lane == leader) base = atomicAdd(&fill[bb], __popcll(m));
    base = __shfl(base, leader);
    if (b == bb) {
      int idx = __popcll(m & ((1ULL << lane) - 1ULL));
      perm[soff[bb] + base + idx] = n;
    }
  }
}

// ---------------------------------------------------------------- embed (MFMA) + weight conversion
__global__ __launch_bounds__(256) void embed_conv(
    const float* __restrict__ x, const float* __restrict__ embW,
    const float* __restrict__ bias, const float* __restrict__ Wrel,
    const float* __restrict__ Wroot, const float* __restrict__ Wl,
    const float* __restrict__ Wr, unsigned short* __restrict__ Bt,
    unsigned short* __restrict__ Btm, unsigned short* __restrict__ out, int N, int nbE) {
  if ((int)blockIdx.x >= nbE) {
    const int R1 = 2 * 128 * 640;
    const int R2 = R1 + 2 * 11 * 128 * 256;
    int t = (blockIdx.x - nbE) * 256 + threadIdx.x;
    if (t < R1) {
      int blk = t / 81920;
      int rem = t % 81920;
      int n = rem / 640;
      int k = rem % 640;
      float v;
      if (k < 512)
        v = Wrel[(size_t)blk * 65536 + (size_t)k * 128 + n];
      else
        v = Wroot[(size_t)blk * 16384 + (size_t)(k - 512) * 128 + n];
      Bt[t] = f2b(v);
    } else if (t < R2) {
      int t2 = t - R1;
      int k = t2 & 255;
      int n = (t2 >> 8) & 127;
      int bb = (t2 >> 15) % 11;
      int blk = t2 / (11 * 128 * 256);
      float v;
      if (k < 128)
        v = Wl[(((size_t)blk * 11 + bb) * 128 + k) * 128 + n];
      else
        v = Wr[(((size_t)blk * 11 + bb) * 128 + (k - 128)) * 128 + n];
      Btm[t2] = f2b(v);
    }
    return;
  }
  __shared__ unsigned char As[64 * 80];
  __shared__ unsigned char Bs[128 * 80];
  int t = threadIdx.x;
  int m0 = blockIdx.x * 64;
  {
    int r = t >> 2, s = t & 3;
    int gr = m0 + r;
    if (gr >= N) gr = N - 1;
    const float* xp = x + (size_t)gr * 32 + s * 8;
    float4 f0 = *(const float4*)xp;
    float4 f1 = *(const float4*)(xp + 4);
    u16x8 o;
    o[0] = f2b(f0.x); o[1] = f2b(f0.y); o[2] = f2b(f0.z); o[3] = f2b(f0.w);
    o[4] = f2b(f1.x); o[5] = f2b(f1.y); o[6] = f2b(f1.z); o[7] = f2b(f1.w);
    *(u16x8*)(As + r * 80 + s * 16) = o;
  }
  {
    int n = t >> 1, hf = t & 1;
    unsigned short tmp[16];
#pragma unroll
    for (int j = 0; j < 16; j++) tmp[j] = f2b(embW[(size_t)(hf * 16 + j) * 128 + n]);
    *(u16x8*)(Bs + n * 80 + hf * 32) = *(u16x8*)tmp;
    *(u16x8*)(Bs + n * 80 + hf * 32 + 16) = *(u16x8*)(tmp + 8);
  }
  __syncthreads();
  int lane = t & 63, wave = t >> 6;
  int row = lane & 15, quad = lane >> 4;
  int nh = wave * 32;
  f32x4 acc[2][4];
#pragma unroll
  for (int i = 0; i < 2; i++)
#pragma unroll
    for (int j = 0; j < 4; j++) acc[i][j] = (f32x4){0.f, 0.f, 0.f, 0.f};
  s16x8 af[4], bf[2];
#pragma unroll
  for (int mt = 0; mt < 4; mt++) {
    int R = mt * 16 + row;
    af[mt] = *(const s16x8*)(As + R * 80 + quad * 16);
  }
#pragma unroll
  for (int nt = 0; nt < 2; nt++) {
    int R = nh + nt * 16 + row;
    bf[nt] = *(const s16x8*)(Bs + R * 80 + quad * 16);
  }
#pragma unroll
  for (int nt = 0; nt < 2; nt++)
#pragma unroll
    for (int mt = 0; mt < 4; mt++)
      acc[nt][mt] = __builtin_amdgcn_mfma_f32_16x16x32_bf16(af[mt], bf[nt], acc[nt][mt], 0, 0, 0);
#pragma unroll
  for (int nt = 0; nt < 2; nt++) {
    int n = nh + nt * 16 + row;
    float bv = bias[n];
#pragma unroll
    for (int mt = 0; mt < 4; mt++) {
#pragma unroll
      for (int r4 = 0; r4 < 4; r4++) {
        int m = m0 + mt * 16 + quad * 4 + r4;
        if (m < N) out[(size_t)m * 128 + n] = f2b(acc[nt][mt][r4] + bv);
      }
    }
  }
}

// ---------------------------------------------------------------- fused gather+GEMM helpers
__device__ __forceinline__ void acc8v(float* a, uint4 v) {
  a[0] += blo(v.x); a[1] += bhi(v.x);
  a[2] += blo(v.y); a[3] += bhi(v.y);
  a[4] += blo(v.z); a[5] += bhi(v.z);
  a[6] += blo(v.w); a[7] += bhi(v.w);
}

// gather 32B (16 cols) of the mean/sum of rows csr[st..st+cn) into a[0..15]
__device__ __forceinline__ void gather_seg(const unsigned short* __restrict__ hb,
                                           const int* __restrict__ csr, int st, int cn,
                                           int chunk, float* a) {
  const unsigned short* hq = hb + chunk * 16;
  int i = 0;
  for (; i + 2 <= cn; i += 2) {
    int p0 = csr[st + i], p1 = csr[st + i + 1];
    const uint4* r0 = (const uint4*)(hq + (size_t)p0 * 128);
    const uint4* r1 = (const uint4*)(hq + (size_t)p1 * 128);
    uint4 v00 = r0[0], v01 = r0[1];
    uint4 v10 = r1[0], v11 = r1[1];
    acc8v(a + 0, v00); acc8v(a + 8, v01);
    acc8v(a + 0, v10); acc8v(a + 8, v11);
  }
  if (i < cn) {
    const uint4* r0 = (const uint4*)(hq + (size_t)csr[st + i] * 128);
    acc8v(a + 0, r0[0]); acc8v(a + 8, r0[1]);
  }
}

// write 16 scaled cols (bf16) into swizzled A tile: row ln, col chunk (16 cols)
__device__ __forceinline__ void write_frag(unsigned char* Ag, int ln, int chunk,
                                           const float* a, float w) {
  int s = chunk >> 2;
#pragma unroll
  for (int h = 0; h < 2; h++) {
    int c = (((chunk & 3) * 2 + h)) ^ (ln & 7);
    const float* p = a + h * 8;
    uint4 o;
    o.x = (unsigned int)f2b(p[0] * w) | ((unsigned int)f2b(p[1] * w) << 16);
    o.y = (unsigned int)f2b(p[2] * w) | ((unsigned int)f2b(p[3] * w) << 16);
    o.z = (unsigned int)f2b(p[4] * w) | ((unsigned int)f2b(p[5] * w) << 16);
    o.w = (unsigned int)f2b(p[6] * w) | ((unsigned int)f2b(p[7] * w) << 16);
    *(uint4*)(Ag + s * 8192 + ln * 128 + (c << 4)) = o;
  }
}

// one 64x128x(K=128) GEMM phase: A = 2 subtiles of [64][128B], B = 2 subtiles of [128][128B]
__device__ __forceinline__ void gemm_tile(const unsigned char* Areg, const unsigned char* Breg,
                                          int row, int quad, int nh, f32x4 acc[2][4]) {
#pragma unroll
  for (int s = 0; s < 2; s++) {
#pragma unroll
    for (int ks = 0; ks < 2; ks++) {
      int cch = ks * 4 + quad;
      s16x8 af[4], bf[2];
#pragma unroll
      for (int mt = 0; mt < 4; mt++) {
        int R = mt * 16 + row;
        af[mt] = *(const s16x8*)(Areg + s * 8192 + R * 128 + ((cch ^ (R & 7)) << 4));
      }
#pragma unroll
      for (int nt = 0; nt < 2; nt++) {
        int R = nh + nt * 16 + row;
        bf[nt] = *(const s16x8*)(Breg + s * 16384 + R * 128 + ((cch ^ (R & 7)) << 4));
      }
#pragma unroll
      for (int nt = 0; nt < 2; nt++)
#pragma unroll
        for (int mt = 0; mt < 4; mt++)
          acc[nt][mt] = __builtin_amdgcn_mfma_f32_16x16x32_bf16(af[mt], bf[nt], acc[nt][mt], 0, 0, 0);
    }
  }
}

// ---------------------------------------------------------------- fused RGCN: gather + GEMM in one kernel
// LDS: Ag 16K + Bs 32K + nodes 256 = 49.4 KB (<64 KB static limit; 3 blocks/CU)
__global__ __launch_bounds__(256) void rgcn_fused(
    const unsigned short* __restrict__ hb, const int* __restrict__ csr,
    const int* __restrict__ seg_start, const int* __restrict__ cnt,
    const float* __restrict__ inv, const int* __restrict__ perm,
    const unsigned short* __restrict__ Bt, const float* __restrict__ bias,
    unsigned short* __restrict__ out) {
  __shared__ unsigned char Ag[16384];   // gathered A tile: 2 subtiles [64][128B]
  __shared__ unsigned char Bs[32768];   // B tile for current phase: 2 subtiles [128][128B]
  __shared__ int nodes[64];
  int t = threadIdx.x;
  int m0 = blockIdx.x * 64;
  if (t < 64) nodes[t] = perm[m0 + t];
  __syncthreads();
  int lane = t & 63, wave = t >> 6;
  int row = lane & 15, quad = lane >> 4;
  int nh = wave * 32;
  int chunk = t & 7, lnb = t >> 3;
  f32x4 acc[2][4];
#pragma unroll
  for (int i = 0; i < 2; i++)
#pragma unroll
    for (int j = 0; j < 4; j++) acc[i][j] = (f32x4){0.f, 0.f, 0.f, 0.f};

  for (int rel = 0; rel < 4; rel++) {
    // stage this relation's B slice (async; overlaps with the gather below)
#pragma unroll
    for (int s = 0; s < 2; s++)
#pragma unroll
      for (int p = 0; p < 4; p++) {
        int o = s * 16384 + p * 4096 + t * 16;
        int r = (o >> 7) & 127, c = ((o >> 4) & 7) ^ (r & 7);
        gld_lds16((const char*)Bt + (size_t)r * 1280 + rel * 256 + s * 128 + c * 16, Bs + o);
      }
    // gather per-(node,rel) mean directly into swizzled LDS A tile
#pragma unroll
    for (int pp = 0; pp < 2; pp++) {
      int ln = pp * 32 + lnb;
      int nd = nodes[ln];
      float a[16];
#pragma unroll
      for (int j = 0; j < 16; j++) a[j] = 0.f;
      float w = 1.f;
      if (nd >= 0) {
        int sid = nd * 4 + rel;
        int st = seg_start[sid], cn2 = cnt[sid];
        w = inv[sid];
        gather_seg(hb, csr, st, cn2, chunk, a);
      }
      write_frag(Ag, ln, chunk, a, w);
    }
    __syncthreads();
    gemm_tile(Ag, Bs, row, quad, nh, acc);
    __syncthreads();
  }
  // root phase: stage Wroot B slice + root-A rows (both async), one barrier, GEMM
#pragma unroll
  for (int s = 0; s < 2; s++)
#pragma unroll
    for (int p = 0; p < 4; p++) {
      int o = s * 16384 + p * 4096 + t * 16;
      int r = (o >> 7) & 127, c = ((o >> 4) & 7) ^ (r & 7);
      gld_lds16((const char*)Bt + (size_t)r * 1280 + 1024 + s * 128 + c * 16, Bs + o);
    }
#pragma unroll
  for (int s = 0; s < 2; s++)
#pragma unroll
    for (int p = 0; p < 2; p++) {
      int o = s * 8192 + p * 4096 + t * 16;
      int r = (o >> 7) & 63, c = ((o >> 4) & 7) ^ (r & 7);
      int nd = nodes[r];
      if (nd < 0) nd = 0;
      gld_lds16((const char*)hb + (size_t)nd * 256 + s * 128 + c * 16, Ag + o);
    }
  __syncthreads();
  gemm_tile(Ag, Bs, row, quad, nh, acc);
#pragma unroll
  for (int nt = 0; nt < 2; nt++) {
    int n = nh + nt * 16 + row;
    float bv = bias[n];
#pragma unroll
    for (int mt = 0; mt < 4; mt++) {
#pragma unroll
      for (int r4 = 0; r4 < 4; r4++) {
        int nd = nodes[mt * 16 + quad * 4 + r4];
        if (nd >= 0) out[(size_t)nd * 128 + n] = f2b(fmaxf(acc[nt][mt][r4] + bv, 0.f));
      }
    }
  }
}

// ---------------------------------------------------------------- fused MFConv
__global__ __launch_bounds__(256) void mf_fused(
    const unsigned short* __restrict__ hb, const int* __restrict__ csr,
    const int* __restrict__ seg_start, const int* __restrict__ deg,
    const int* __restrict__ perm, const int* __restrict__ hist,
    const unsigned short* __restrict__ Bt, const float* __restrict__ bl,
    unsigned short* __restrict__ out, int relu_out) {
  __shared__ unsigned char Ag[16384];
  __shared__ unsigned char Bs[32768];
  __shared__ int nodes[64];
  __shared__ int soff[NBUCK + 1];
  int t = threadIdx.x;
  int m0 = blockIdx.x * 64;
  if (t == 0) {
    int a2 = 0;
    for (int b2 = 0; b2 < NBUCK; b2++) {
      soff[b2] = a2;
      a2 += ((hist[b2] + 63) >> 6) << 6;
    }
    soff[NBUCK] = a2;
  }
  if (t < 64) nodes[t] = perm[m0 + t];
  __syncthreads();
  if (m0 >= soff[NBUCK]) return;
  int b = 0;
  while (b < 10 && m0 >= soff[b + 1]) b++;
  const unsigned short* Bb = Bt + (size_t)b * 128 * 256;
  // stage B phase-1 (Wl), async
#pragma unroll
  for (int s = 0; s < 2; s++)
#pragma unroll
    for (int p = 0; p < 4; p++) {
      int o = s * 16384 + p * 4096 + t * 16;
      int r = (o >> 7) & 127, c = ((o >> 4) & 7) ^ (r & 7);
      gld_lds16((const char*)Bb + (size_t)r * 512 + s * 128 + c * 16, Bs + o);
    }
  int lane = t & 63, wave = t >> 6;
  int row = lane & 15, quad = lane >> 4;
  int nh = wave * 32;
  int chunk = t & 7, lnb = t >> 3;
  f32x4 acc[2][4];
#pragma unroll
  for (int i = 0; i < 2; i++)
#pragma unroll
    for (int j = 0; j < 4; j++) acc[i][j] = (f32x4){0.f, 0.f, 0.f, 0.f};
  // gather neighbor-sum into Ag
#pragma unroll
  for (int pp = 0; pp < 2; pp++) {
    int ln = pp * 32 + lnb;
    int nd = nodes[ln];
    float a[16];
#pragma unroll
    for (int j = 0; j < 16; j++) a[j] = 0.f;
    if (nd >= 0) gather_seg(hb, csr, seg_start[nd * 4], deg[nd], chunk, a);
    write_frag(Ag, ln, chunk, a, 1.f);
  }
  __syncthreads();
  gemm_tile(Ag, Bs, row, quad, nh, acc);
  __syncthreads();
  // phase-2: stage B (Wr) + root-A rows into Ag (both async), one barrier, GEMM
#pragma unroll
  for (int s = 0; s < 2; s++)
#pragma unroll
    for (int p = 0; p < 4; p++) {
      int o = s * 16384 + p * 4096 + t * 16;
      int r = (o >> 7) & 127, c = ((o >> 4) & 7) ^ (r & 7);
      gld_lds16((const char*)Bb + (size_t)r * 512 + 256 + s * 128 + c * 16, Bs + o);
    }
#pragma unroll
  for (int s = 0; s < 2; s++)
#pragma unroll
    for (int p = 0; p < 2; p++) {
      int o = s * 8192 + p * 4096 + t * 16;
      int r = (o >> 7) & 63, c = ((o >> 4) & 7) ^ (r & 7);
      int nd = nodes[r];
      if (nd < 0) nd = 0;
      gld_lds16((const char*)hb + (size_t)nd * 256 + s * 128 + c * 16, Ag + o);
    }
  __syncthreads();
  gemm_tile(Ag, Bs, row, quad, nh, acc);
  const float* bb = bl + b * 128;
#pragma unroll
  for (int nt = 0; nt < 2; nt++) {
    int n = nh + nt * 16 + row;
    float bv = bb[n];
#pragma unroll
    for (int mt = 0; mt < 4; mt++) {
#pragma unroll
      for (int r4 = 0; r4 < 4; r4++) {
        int nd = nodes[mt * 16 + quad * 4 + r4];
        if (nd >= 0) {
          float v = acc[nt][mt][r4] + bv;
          if (relu_out) v = fmaxf(v, 0.f);
          out[(size_t)nd * 128 + n] = f2b(v);
        }
      }
    }
  }
}

// ---------------------------------------------------------------- pool + head
__global__ void pool2(const unsigned short* __restrict__ h, const int* __restrict__ batch,
                      float* __restrict__ g, int N, int G) {
  int gr = blockIdx.x / POOL_CHUNKS;
  int ck = blockIdx.x % POOL_CHUNKS;
  int t = threadIdx.x;
  int lane = t & 63, grp = t >> 6;
  int lo = 0, hi = N;
  while (lo < hi) {
    int m = (lo + hi) >> 1;
    if (batch[m] < gr) lo = m + 1; else hi = m;
  }
  int s = lo;
  lo = s; hi = N;
  while (lo < hi) {
    int m = (lo + hi) >> 1;
    if (batch[m] < gr + 1) lo = m + 1; else hi = m;
  }
  int e = lo;
  int len = e - s;
  int a = s + (int)(((long long)len * ck) / POOL_CHUNKS);
  int b = s + (int)(((long long)len * (ck + 1)) / POOL_CHUNKS);
  float s0 = 0.f, s1 = 0.f;
  for (int n = a + grp; n < b; n += 2) {
    unsigned int v = *(const unsigned int*)(h + (size_t)n * 128 + lane * 2);
    s0 += blo(v);
    s1 += bhi(v);
  }
  if (b > a + grp) {
    atomicAdd(&g[gr * 128 + lane * 2], s0);
    atomicAdd(&g[gr * 128 + lane * 2 + 1], s1);
  }
}

__global__ void head_kernel(const float* __restrict__ g, const float* __restrict__ W1,
                            const float* __restrict__ b1, const float* __restrict__ W2,
                            const float* __restrict__ b2, float* __restrict__ out) {
  int bg = blockIdx.x;
  int o = threadIdx.x;
  __shared__ float gs[128];
  __shared__ float red[128];
  gs[o] = g[bg * 128 + o];
  __syncthreads();
  float acc = b1[o];
  for (int k = 0; k < 128; k++) acc += gs[k] * W1[k * 128 + o];
  acc = fmaxf(acc, 0.f);
  red[o] = acc * W2[o];
  __syncthreads();
  for (int s = 64; s > 0; s >>= 1) {
    if (o < s) red[o] += red[o + s];
    __syncthreads();
  }
  if (o == 0) out[bg] = red[0] + b2[0];
}

// ---------------------------------------------------------------- launch
extern "C" void kernel_launch(void* const* d_in, const int* in_sizes, int n_in,
                              void* d_out, int out_size, void* d_ws, size_t ws_size,
                              hipStream_t stream) {
  const float* x = (const float*)d_in[0];
  const int* ei = (const int*)d_in[1];
  const int* ea = (const int*)d_in[2];
  const int* batch = (const int*)d_in[3];
  const float* embW = (const float*)d_in[4];
  const float* embB = (const float*)d_in[5];
  const float* Wrel = (const float*)d_in[6];
  const float* Wroot = (const float*)d_in[7];
  const float* rb = (const float*)d_in[8];
  const float* Wl = (const float*)d_in[9];
  const float* bl = (const float*)d_in[10];
  const float* Wr = (const float*)d_in[11];
  const float* l1W = (const float*)d_in[12];
  const float* l1b = (const float*)d_in[13];
  const float* l2W = (const float*)d_in[14];
  const float* l2b = (const float*)d_in[15];
  float* out = (float*)d_out;

  int N = in_sizes[0] / 32;
  int E = in_sizes[2];
  int G = out_size;
  int NSEG = N * 4;
  int NB = (N + 127) >> 7;

  char* p = (char*)d_ws;
  auto alloc = [&](size_t bytes) {
    char* r = p;
    p += (bytes + 255) & ~(size_t)255;
    return r;
  };
  int permCap = ((N + 63) / 64 + NBUCK) * 64;
  unsigned short* h_bf = (unsigned short*)alloc((size_t)N * 128 * 2);
  unsigned short* h2_bf = (unsigned short*)alloc((size_t)N * 128 * 2);
  unsigned short* Btr = (unsigned short*)alloc((size_t)2 * 128 * 640 * 2);
  unsigned short* Btm = (unsigned short*)alloc((size_t)2 * 11 * 128 * 256 * 2);
  float* inv = (float*)alloc((size_t)NSEG * 4);
  int* cnt = (int*)alloc((size_t)NSEG * 4);
  int* seg_start = (int*)alloc((size_t)NSEG * 4);
  int* csr = (int*)alloc((size_t)E * 4);
  uint2* ebuf = (uint2*)alloc((size_t)E * 8);
  int* deg = (int*)alloc((size_t)N * 4);
  int* bucket = (int*)alloc((size_t)N * 4);
  int* perm = (int*)alloc((size_t)permCap * 4);
  int* boff = (int*)alloc(516 * 4);
  int* bcur = (int*)alloc(512 * 4);
  size_t zeroBytes = 8192 + (size_t)G * 128 * 4;
  char* zb = alloc(zeroBytes);
  int* bhist = (int*)zb;
  int* hist = (int*)(zb + 4096);
  int* fill = (int*)(zb + 4224);
  int* done = (int*)(zb + 4352);
  float* g = (float*)(zb + 8192);

  (void)hipMemsetAsync(zb, 0, zeroBytes, stream);

  const int* src = ei;
  const int* dst = ei + E;

  int sblocks = (E + 4095) / 4096;
  coarse_count_scan<<<sblocks, 512, 0, stream>>>(dst, bhist, boff, bcur, done, perm, permCap,
                                                 NB, E, sblocks);
  coarse_scatter<<<sblocks, 512, 0, stream>>>(src, dst, ea, bcur, ebuf, E);
  fine_place<<<NB, 512, 0, stream>>>(ebuf, boff, cnt, seg_start, inv, deg, bucket, hist, csr,
                                     NSEG);
  build_perm<<<(N + 255) / 256, 256, 0, stream>>>(bucket, hist, fill, perm, N);

  int nbE = (N + 63) / 64;
  int convBlocks = (2 * 128 * 640 + 2 * 11 * 128 * 256 + 255) / 256;
  embed_conv<<<nbE + convBlocks, 256, 0, stream>>>(x, embW, embB, Wrel, Wroot, Wl, Wr, Btr,
                                                   Btm, h_bf, N, nbE);

  int mfblocks = permCap / 64;
  for (int blk = 0; blk < 2; blk++) {
    rgcn_fused<<<mfblocks, 256, 0, stream>>>(h_bf, csr, seg_start, cnt, inv, perm,
                                             Btr + (size_t)blk * 81920, rb + blk * 128,
                                             h2_bf);
    mf_fused<<<mfblocks, 256, 0, stream>>>(h2_bf, csr, seg_start, deg, perm, hist,
                                           Btm + (size_t)blk * 11 * 128 * 256,
                                           bl + (size_t)blk * 11 * 128, h_bf,
                                           (blk == 0) ? 1 : 0);
  }
  pool2<<<G * POOL_CHUNKS, 128, 0, stream>>>(h_bf, batch, g, N, G);
  head_kernel<<<G, 128, 0, stream>>>(g, l1W, l1b, l2W, l2b, out);
}

// Round 3
// 406.206 us; speedup vs baseline: 1.1631x; 1.1631x over previous
//
#include <hip/hip_runtime.h>
#include <hip/hip_bf16.h>

#define NRELS 4
#define MAXDEG 10
#define NBUCK 11
#define POOL_CHUNKS 8

typedef __attribute__((ext_vector_type(8))) short s16x8;
typedef __attribute__((ext_vector_type(4))) float f32x4;
typedef __attribute__((ext_vector_type(8))) unsigned short u16x8;

__device__ inline unsigned short f2b(float f) {
  __hip_bfloat16 h = __float2bfloat16(f);
  return *reinterpret_cast<unsigned short*>(&h);
}
__device__ inline float b2f(unsigned short u) {
  union { unsigned int i; float f; } v;
  v.i = ((unsigned int)u) << 16;
  return v.f;
}
__device__ inline float blo(unsigned int v) {
  union { unsigned int i; float f; } x;
  x.i = v << 16;
  return x.f;
}
__device__ inline float bhi(unsigned int v) {
  union { unsigned int i; float f; } x;
  x.i = v & 0xffff0000u;
  return x.f;
}

typedef __attribute__((address_space(3))) unsigned int lds_uint;
typedef __attribute__((address_space(1))) const unsigned int glob_uint;
__device__ __forceinline__ void gld_lds16(const void* g, void* l) {
  __builtin_amdgcn_global_load_lds((glob_uint*)g, (lds_uint*)l, 16, 0, 0);
}

// ================================================================ CSR build
__global__ __launch_bounds__(512) void coarse_count_scan(
    const int* __restrict__ dst, int* __restrict__ bhist, int* __restrict__ boff,
    int* __restrict__ bcur, int* __restrict__ done, int* __restrict__ perm, int permCap,
    int NB, int E, int nblocks) {
  __shared__ int lh[512];
  __shared__ int lastf;
  int t = threadIdx.x;
  lh[t] = 0;
  __syncthreads();
  for (int i = blockIdx.x * 512 + t; i < permCap; i += nblocks * 512) perm[i] = -1;
  int base = blockIdx.x * 4096;
  int lim = E - base;
  if (lim > 4096) lim = 4096;
  for (int i = t; i < lim; i += 512) atomicAdd(&lh[dst[base + i] >> 7], 1);
  __syncthreads();
  if (lh[t]) atomicAdd(&bhist[t], lh[t]);
  __threadfence();
  __syncthreads();
  if (t == 0) lastf = (atomicAdd(done, 1) == nblocks - 1) ? 1 : 0;
  __syncthreads();
  if (!lastf) return;
  int v = (t < NB) ? atomicAdd(&bhist[t], 0) : 0;
  lh[t] = v;
  __syncthreads();
  for (int o = 1; o < 512; o <<= 1) {
    int x = (t >= o) ? lh[t - o] : 0;
    __syncthreads();
    lh[t] += x;
    __syncthreads();
  }
  if (t < NB) {
    int st = lh[t] - v;
    boff[t] = st;
    bcur[t] = st;
  }
  if (t == 0) boff[NB] = E;
}

__global__ __launch_bounds__(512) void coarse_scatter(
    const int* __restrict__ src, const int* __restrict__ dst, const int* __restrict__ rel,
    int* __restrict__ bcur, uint2* __restrict__ ebuf, int E) {
  __shared__ int lhist[512];
  __shared__ int lstart[512];
  __shared__ int lcur[512];
  __shared__ int gbase[512];
  __shared__ uint2 stage[4096];
  int t = threadIdx.x;
  lhist[t] = 0;
  __syncthreads();
  int base = blockIdx.x * 4096;
  int lim = E - base;
  if (lim > 4096) lim = 4096;
  for (int i = t; i < lim; i += 512) atomicAdd(&lhist[dst[base + i] >> 7], 1);
  __syncthreads();
  int myc = lhist[t];
  lstart[t] = myc;
  __syncthreads();
  for (int o = 1; o < 512; o <<= 1) {
    int x = (t >= o) ? lstart[t - o] : 0;
    __syncthreads();
    lstart[t] += x;
    __syncthreads();
  }
  int incl = lstart[t];
  __syncthreads();
  lstart[t] = incl - myc;
  lcur[t] = 0;
  if (myc > 0) gbase[t] = atomicAdd(&bcur[t], myc);
  __syncthreads();
  for (int i = t; i < lim; i += 512) {
    int e = base + i;
    int d = dst[e];
    int b = d >> 7;
    int slot = lstart[b] + atomicAdd(&lcur[b], 1);
    stage[slot] = make_uint2((unsigned)(d * 4 + rel[e]), (unsigned)src[e]);
  }
  __syncthreads();
  for (int i = t; i < lim; i += 512) {
    uint2 val = stage[i];
    int b = (int)(val.x >> 9);
    ebuf[gbase[b] + (i - lstart[b])] = val;
  }
}

__global__ __launch_bounds__(512) void fine_place(
    const uint2* __restrict__ ebuf, const int* __restrict__ boff, int* __restrict__ cnt,
    int* __restrict__ seg_start, float* __restrict__ inv, int* __restrict__ deg,
    int* __restrict__ bucket, int* __restrict__ hist, int* __restrict__ csr, int NSEG) {
  __shared__ int lh[512];
  __shared__ int sc[512];
  __shared__ int lcur[512];
  __shared__ int lbh[16];
  int t = threadIdx.x;
  int b = blockIdx.x;
  lh[t] = 0;
  if (t < 16) lbh[t] = 0;
  __syncthreads();
  int s = boff[b], e = boff[b + 1];
  for (int i = s + t; i < e; i += 512) atomicAdd(&lh[ebuf[i].x & 511], 1);
  __syncthreads();
  int v = lh[t];
  sc[t] = v;
  __syncthreads();
  for (int o = 1; o < 512; o <<= 1) {
    int x = (t >= o) ? sc[t - o] : 0;
    __syncthreads();
    sc[t] += x;
    __syncthreads();
  }
  int gseg = b * 512 + t;
  int mystart = s + sc[t] - v;
  lcur[t] = mystart;
  if (gseg < NSEG) {
    cnt[gseg] = v;
    seg_start[gseg] = mystart;
    inv[gseg] = 1.0f / (float)(v > 1 ? v : 1);
    if ((t & 3) == 0) {
      int d = sc[t + 3] - sc[t] + v;
      int n = gseg >> 2;
      deg[n] = d;
      int bk = d < MAXDEG ? d : MAXDEG;
      bucket[n] = bk;
      atomicAdd(&lbh[bk], 1);
    }
  }
  __syncthreads();
  if (t < NBUCK && lbh[t]) atomicAdd(&hist[t], lbh[t]);
  for (int i = s + t; i < e; i += 512) {
    uint2 vv = ebuf[i];
    int pos = atomicAdd(&lcur[vv.x & 511], 1);
    csr[pos] = (int)vv.y;
  }
}

__global__ void build_perm(const int* __restrict__ bucket, const int* __restrict__ hist,
                           int* __restrict__ fill, int* __restrict__ perm, int N) {
  __shared__ int soff[NBUCK];
  if (threadIdx.x == 0) {
    int acc = 0;
    for (int b = 0; b < NBUCK; b++) {
      soff[b] = acc;
      acc += ((hist[b] + 63) >> 6) << 6;
    }
  }
  __syncthreads();
  int n = blockIdx.x * 256 + threadIdx.x;
  int b = (n < N) ? bucket[n] : -1;
  int lane = threadIdx.x & 63;
  for (int bb = 0; bb < NBUCK; bb++) {
    unsigned long long m = __ballot(b == bb);
    if (m == 0ULL) continue;
    int leader = __ffsll(m) - 1;
    int base = 0;
    if (lane == leader) base = atomicAdd(&fill[bb], __popcll(m));
    base = __shfl(base, leader);
    if (b == bb) {
      int idx = __popcll(m & ((1ULL << lane) - 1ULL));
      perm[soff[bb] + base + idx] = n;
    }
  }
}

// ---------------------------------------------------------------- embed (MFMA) + weight conversion
__global__ __launch_bounds__(256) void embed_conv(
    const float* __restrict__ x, const float* __restrict__ embW,
    const float* __restrict__ bias, const float* __restrict__ Wrel,
    const float* __restrict__ Wroot, const float* __restrict__ Wl,
    const float* __restrict__ Wr, unsigned short* __restrict__ Bt,
    unsigned short* __restrict__ Btm, unsigned short* __restrict__ out, int N, int nbE) {
  if ((int)blockIdx.x >= nbE) {
    const int R1 = 2 * 128 * 640;
    const int R2 = R1 + 2 * 11 * 128 * 256;
    int t = (blockIdx.x - nbE) * 256 + threadIdx.x;
    if (t < R1) {
      int blk = t / 81920;
      int rem = t % 81920;
      int n = rem / 640;
      int k = rem % 640;
      float v;
      if (k < 512)
        v = Wrel[(size_t)blk * 65536 + (size_t)k * 128 + n];
      else
        v = Wroot[(size_t)blk * 16384 + (size_t)(k - 512) * 128 + n];
      Bt[t] = f2b(v);
    } else if (t < R2) {
      int t2 = t - R1;
      int k = t2 & 255;
      int n = (t2 >> 8) & 127;
      int bb = (t2 >> 15) % 11;
      int blk = t2 / (11 * 128 * 256);
      float v;
      if (k < 128)
        v = Wl[(((size_t)blk * 11 + bb) * 128 + k) * 128 + n];
      else
        v = Wr[(((size_t)blk * 11 + bb) * 128 + (k - 128)) * 128 + n];
      Btm[t2] = f2b(v);
    }
    return;
  }
  __shared__ unsigned char As[64 * 80];
  __shared__ unsigned char Bs[128 * 80];
  int t = threadIdx.x;
  int m0 = blockIdx.x * 64;
  {
    int r = t >> 2, s = t & 3;
    int gr = m0 + r;
    if (gr >= N) gr = N - 1;
    const float* xp = x + (size_t)gr * 32 + s * 8;
    float4 f0 = *(const float4*)xp;
    float4 f1 = *(const float4*)(xp + 4);
    u16x8 o;
    o[0] = f2b(f0.x); o[1] = f2b(f0.y); o[2] = f2b(f0.z); o[3] = f2b(f0.w);
    o[4] = f2b(f1.x); o[5] = f2b(f1.y); o[6] = f2b(f1.z); o[7] = f2b(f1.w);
    *(u16x8*)(As + r * 80 + s * 16) = o;
  }
  {
    int n = t >> 1, hf = t & 1;
    unsigned short tmp[16];
#pragma unroll
    for (int j = 0; j < 16; j++) tmp[j] = f2b(embW[(size_t)(hf * 16 + j) * 128 + n]);
    *(u16x8*)(Bs + n * 80 + hf * 32) = *(u16x8*)tmp;
    *(u16x8*)(Bs + n * 80 + hf * 32 + 16) = *(u16x8*)(tmp + 8);
  }
  __syncthreads();
  int lane = t & 63, wave = t >> 6;
  int row = lane & 15, quad = lane >> 4;
  int nh = wave * 32;
  f32x4 acc[2][4];
#pragma unroll
  for (int i = 0; i < 2; i++)
#pragma unroll
    for (int j = 0; j < 4; j++) acc[i][j] = (f32x4){0.f, 0.f, 0.f, 0.f};
  s16x8 af[4], bf[2];
#pragma unroll
  for (int mt = 0; mt < 4; mt++) {
    int R = mt * 16 + row;
    af[mt] = *(const s16x8*)(As + R * 80 + quad * 16);
  }
#pragma unroll
  for (int nt = 0; nt < 2; nt++) {
    int R = nh + nt * 16 + row;
    bf[nt] = *(const s16x8*)(Bs + R * 80 + quad * 16);
  }
#pragma unroll
  for (int nt = 0; nt < 2; nt++)
#pragma unroll
    for (int mt = 0; mt < 4; mt++)
      acc[nt][mt] = __builtin_amdgcn_mfma_f32_16x16x32_bf16(af[mt], bf[nt], acc[nt][mt], 0, 0, 0);
#pragma unroll
  for (int nt = 0; nt < 2; nt++) {
    int n = nh + nt * 16 + row;
    float bv = bias[n];
#pragma unroll
    for (int mt = 0; mt < 4; mt++) {
#pragma unroll
      for (int r4 = 0; r4 < 4; r4++) {
        int m = m0 + mt * 16 + quad * 4 + r4;
        if (m < N) out[(size_t)m * 128 + n] = f2b(acc[nt][mt][r4] + bv);
      }
    }
  }
}

// ---------------------------------------------------------------- fused gather+GEMM helpers
__device__ __forceinline__ void acc8v(float* a, uint4 v) {
  a[0] += blo(v.x); a[1] += bhi(v.x);
  a[2] += blo(v.y); a[3] += bhi(v.y);
  a[4] += blo(v.z); a[5] += bhi(v.z);
  a[6] += blo(v.w); a[7] += bhi(v.w);
}

// gather 32B (16 cols) of the mean/sum of rows csr[st..st+cn) into a[0..15]
__device__ __forceinline__ void gather_seg(const unsigned short* __restrict__ hb,
                                           const int* __restrict__ csr, int st, int cn,
                                           int chunk, float* a) {
  const unsigned short* hq = hb + chunk * 16;
  int i = 0;
  for (; i + 2 <= cn; i += 2) {
    int p0 = csr[st + i], p1 = csr[st + i + 1];
    const uint4* r0 = (const uint4*)(hq + (size_t)p0 * 128);
    const uint4* r1 = (const uint4*)(hq + (size_t)p1 * 128);
    uint4 v00 = r0[0], v01 = r0[1];
    uint4 v10 = r1[0], v11 = r1[1];
    acc8v(a + 0, v00); acc8v(a + 8, v01);
    acc8v(a + 0, v10); acc8v(a + 8, v11);
  }
  if (i < cn) {
    const uint4* r0 = (const uint4*)(hq + (size_t)csr[st + i] * 128);
    acc8v(a + 0, r0[0]); acc8v(a + 8, r0[1]);
  }
}

// write 16 scaled cols (bf16) into swizzled A tile: row ln, col chunk (16 cols)
__device__ __forceinline__ void write_frag(unsigned char* Ag, int ln, int chunk,
                                           const float* a, float w) {
  int s = chunk >> 2;
#pragma unroll
  for (int h = 0; h < 2; h++) {
    int c = (((chunk & 3) * 2 + h)) ^ (ln & 7);
    const float* p = a + h * 8;
    uint4 o;
    o.x = (unsigned int)f2b(p[0] * w) | ((unsigned int)f2b(p[1] * w) << 16);
    o.y = (unsigned int)f2b(p[2] * w) | ((unsigned int)f2b(p[3] * w) << 16);
    o.z = (unsigned int)f2b(p[4] * w) | ((unsigned int)f2b(p[5] * w) << 16);
    o.w = (unsigned int)f2b(p[6] * w) | ((unsigned int)f2b(p[7] * w) << 16);
    *(uint4*)(Ag + s * 8192 + ln * 128 + (c << 4)) = o;
  }
}

// one 64x128x(K=128) GEMM phase; A from swizzled LDS, B fragments direct from
// global (L2-hot weight table). Bp = phase base (bytes), strideB = row stride bytes.
__device__ __forceinline__ void gemm_tile_gB(const unsigned char* Areg, const char* Bp,
                                             int strideB, int row, int quad, int nh,
                                             f32x4 acc[2][4]) {
#pragma unroll
  for (int s = 0; s < 2; s++) {
#pragma unroll
    for (int ks = 0; ks < 2; ks++) {
      int cch = ks * 4 + quad;
      s16x8 af[4], bf[2];
#pragma unroll
      for (int mt = 0; mt < 4; mt++) {
        int R = mt * 16 + row;
        af[mt] = *(const s16x8*)(Areg + s * 8192 + R * 128 + ((cch ^ (R & 7)) << 4));
      }
#pragma unroll
      for (int nt = 0; nt < 2; nt++) {
        int R = nh + nt * 16 + row;
        bf[nt] = *(const s16x8*)(Bp + (size_t)R * strideB + s * 128 + cch * 16);
      }
#pragma unroll
      for (int nt = 0; nt < 2; nt++)
#pragma unroll
        for (int mt = 0; mt < 4; mt++)
          acc[nt][mt] = __builtin_amdgcn_mfma_f32_16x16x32_bf16(af[mt], bf[nt], acc[nt][mt], 0, 0, 0);
    }
  }
}

// ---------------------------------------------------------------- fused RGCN
// LDS: Ag 16K + nodes 256B = 16.6 KB -> residency VGPR-capped (~6-7 blocks/CU)
__global__ __launch_bounds__(256) void rgcn_fused(
    const unsigned short* __restrict__ hb, const int* __restrict__ csr,
    const int* __restrict__ seg_start, const int* __restrict__ cnt,
    const float* __restrict__ inv, const int* __restrict__ perm,
    const unsigned short* __restrict__ Bt, const float* __restrict__ bias,
    unsigned short* __restrict__ out) {
  __shared__ unsigned char Ag[16384];   // gathered A tile: 2 subtiles [64][128B]
  __shared__ int nodes[64];
  int t = threadIdx.x;
  int m0 = blockIdx.x * 64;
  if (t < 64) nodes[t] = perm[m0 + t];
  __syncthreads();
  int lane = t & 63, wave = t >> 6;
  int row = lane & 15, quad = lane >> 4;
  int nh = wave * 32;
  int chunk = t & 7, lnb = t >> 3;
  f32x4 acc[2][4];
#pragma unroll
  for (int i = 0; i < 2; i++)
#pragma unroll
    for (int j = 0; j < 4; j++) acc[i][j] = (f32x4){0.f, 0.f, 0.f, 0.f};

  for (int rel = 0; rel < 4; rel++) {
    // gather per-(node,rel) mean directly into swizzled LDS A tile
#pragma unroll
    for (int pp = 0; pp < 2; pp++) {
      int ln = pp * 32 + lnb;
      int nd = nodes[ln];
      float a[16];
#pragma unroll
      for (int j = 0; j < 16; j++) a[j] = 0.f;
      float w = 1.f;
      if (nd >= 0) {
        int sid = nd * 4 + rel;
        int st = seg_start[sid], cn2 = cnt[sid];
        w = inv[sid];
        gather_seg(hb, csr, st, cn2, chunk, a);
      }
      write_frag(Ag, ln, chunk, a, w);
    }
    __syncthreads();
    gemm_tile_gB(Ag, (const char*)Bt + rel * 256, 1280, row, quad, nh, acc);
    __syncthreads();
  }
  // root phase: async-stage root-A rows into Ag; B (Wroot) direct from L2
#pragma unroll
  for (int s = 0; s < 2; s++)
#pragma unroll
    for (int p = 0; p < 2; p++) {
      int o = s * 8192 + p * 4096 + t * 16;
      int r = (o >> 7) & 63, c = ((o >> 4) & 7) ^ (r & 7);
      int nd = nodes[r];
      if (nd < 0) nd = 0;
      gld_lds16((const char*)hb + (size_t)nd * 256 + s * 128 + c * 16, Ag + o);
    }
  __syncthreads();
  gemm_tile_gB(Ag, (const char*)Bt + 1024, 1280, row, quad, nh, acc);
#pragma unroll
  for (int nt = 0; nt < 2; nt++) {
    int n = nh + nt * 16 + row;
    float bv = bias[n];
#pragma unroll
    for (int mt = 0; mt < 4; mt++) {
#pragma unroll
      for (int r4 = 0; r4 < 4; r4++) {
        int nd = nodes[mt * 16 + quad * 4 + r4];
        if (nd >= 0) out[(size_t)nd * 128 + n] = f2b(fmaxf(acc[nt][mt][r4] + bv, 0.f));
      }
    }
  }
}

// ---------------------------------------------------------------- fused MFConv
__global__ __launch_bounds__(256) void mf_fused(
    const unsigned short* __restrict__ hb, const int* __restrict__ csr,
    const int* __restrict__ seg_start, const int* __restrict__ deg,
    const int* __restrict__ perm, const int* __restrict__ hist,
    const unsigned short* __restrict__ Bt, const float* __restrict__ bl,
    unsigned short* __restrict__ out, int relu_out) {
  __shared__ unsigned char Ag[16384];
  __shared__ int nodes[64];
  __shared__ int soff[NBUCK + 1];
  int t = threadIdx.x;
  int m0 = blockIdx.x * 64;
  if (t == 0) {
    int a2 = 0;
    for (int b2 = 0; b2 < NBUCK; b2++) {
      soff[b2] = a2;
      a2 += ((hist[b2] + 63) >> 6) << 6;
    }
    soff[NBUCK] = a2;
  }
  if (t < 64) nodes[t] = perm[m0 + t];
  __syncthreads();
  if (m0 >= soff[NBUCK]) return;
  int b = 0;
  while (b < 10 && m0 >= soff[b + 1]) b++;
  const char* Bb = (const char*)(Bt + (size_t)b * 128 * 256);
  int lane = t & 63, wave = t >> 6;
  int row = lane & 15, quad = lane >> 4;
  int nh = wave * 32;
  int chunk = t & 7, lnb = t >> 3;
  f32x4 acc[2][4];
#pragma unroll
  for (int i = 0; i < 2; i++)
#pragma unroll
    for (int j = 0; j < 4; j++) acc[i][j] = (f32x4){0.f, 0.f, 0.f, 0.f};
  // gather neighbor-sum into Ag
#pragma unroll
  for (int pp = 0; pp < 2; pp++) {
    int ln = pp * 32 + lnb;
    int nd = nodes[ln];
    float a[16];
#pragma unroll
    for (int j = 0; j < 16; j++) a[j] = 0.f;
    if (nd >= 0) gather_seg(hb, csr, seg_start[nd * 4], deg[nd], chunk, a);
    write_frag(Ag, ln, chunk, a, 1.f);
  }
  __syncthreads();
  gemm_tile_gB(Ag, Bb, 512, row, quad, nh, acc);   // Wl phase
  __syncthreads();
  // phase-2: async-stage root-A into Ag; B (Wr) direct from L2
#pragma unroll
  for (int s = 0; s < 2; s++)
#pragma unroll
    for (int p = 0; p < 2; p++) {
      int o = s * 8192 + p * 4096 + t * 16;
      int r = (o >> 7) & 63, c = ((o >> 4) & 7) ^ (r & 7);
      int nd = nodes[r];
      if (nd < 0) nd = 0;
      gld_lds16((const char*)hb + (size_t)nd * 256 + s * 128 + c * 16, Ag + o);
    }
  __syncthreads();
  gemm_tile_gB(Ag, Bb + 256, 512, row, quad, nh, acc);  // Wr phase
  const float* bb = bl + b * 128;
#pragma unroll
  for (int nt = 0; nt < 2; nt++) {
    int n = nh + nt * 16 + row;
    float bv = bb[n];
#pragma unroll
    for (int mt = 0; mt < 4; mt++) {
#pragma unroll
      for (int r4 = 0; r4 < 4; r4++) {
        int nd = nodes[mt * 16 + quad * 4 + r4];
        if (nd >= 0) {
          float v = acc[nt][mt][r4] + bv;
          if (relu_out) v = fmaxf(v, 0.f);
          out[(size_t)nd * 128 + n] = f2b(v);
        }
      }
    }
  }
}

// ---------------------------------------------------------------- pool + head
__global__ void pool2(const unsigned short* __restrict__ h, const int* __restrict__ batch,
                      float* __restrict__ g, int N, int G) {
  int gr = blockIdx.x / POOL_CHUNKS;
  int ck = blockIdx.x % POOL_CHUNKS;
  int t = threadIdx.x;
  int lane = t & 63, grp = t >> 6;
  int lo = 0, hi = N;
  while (lo < hi) {
    int m = (lo + hi) >> 1;
    if (batch[m] < gr) lo = m + 1; else hi = m;
  }
  int s = lo;
  lo = s; hi = N;
  while (lo < hi) {
    int m = (lo + hi) >> 1;
    if (batch[m] < gr + 1) lo = m + 1; else hi = m;
  }
  int e = lo;
  int len = e - s;
  int a = s + (int)(((long long)len * ck) / POOL_CHUNKS);
  int b = s + (int)(((long long)len * (ck + 1)) / POOL_CHUNKS);
  float s0 = 0.f, s1 = 0.f;
  for (int n = a + grp; n < b; n += 2) {
    unsigned int v = *(const unsigned int*)(h + (size_t)n * 128 + lane * 2);
    s0 += blo(v);
    s1 += bhi(v);
  }
  if (b > a + grp) {
    atomicAdd(&g[gr * 128 + lane * 2], s0);
    atomicAdd(&g[gr * 128 + lane * 2 + 1], s1);
  }
}

__global__ void head_kernel(const float* __restrict__ g, const float* __restrict__ W1,
                            const float* __restrict__ b1, const float* __restrict__ W2,
                            const float* __restrict__ b2, float* __restrict__ out) {
  int bg = blockIdx.x;
  int o = threadIdx.x;
  __shared__ float gs[128];
  __shared__ float red[128];
  gs[o] = g[bg * 128 + o];
  __syncthreads();
  float acc = b1[o];
  for (int k = 0; k < 128; k++) acc += gs[k] * W1[k * 128 + o];
  acc = fmaxf(acc, 0.f);
  red[o] = acc * W2[o];
  __syncthreads();
  for (int s = 64; s > 0; s >>= 1) {
    if (o < s) red[o] += red[o + s];
    __syncthreads();
  }
  if (o == 0) out[bg] = red[0] + b2[0];
}

// ---------------------------------------------------------------- launch
extern "C" void kernel_launch(void* const* d_in, const int* in_sizes, int n_in,
                              void* d_out, int out_size, void* d_ws, size_t ws_size,
                              hipStream_t stream) {
  const float* x = (const float*)d_in[0];
  const int* ei = (const int*)d_in[1];
  const int* ea = (const int*)d_in[2];
  const int* batch = (const int*)d_in[3];
  const float* embW = (const float*)d_in[4];
  const float* embB = (const float*)d_in[5];
  const float* Wrel = (const float*)d_in[6];
  const float* Wroot = (const float*)d_in[7];
  const float* rb = (const float*)d_in[8];
  const float* Wl = (const float*)d_in[9];
  const float* bl = (const float*)d_in[10];
  const float* Wr = (const float*)d_in[11];
  const float* l1W = (const float*)d_in[12];
  const float* l1b = (const float*)d_in[13];
  const float* l2W = (const float*)d_in[14];
  const float* l2b = (const float*)d_in[15];
  float* out = (float*)d_out;

  int N = in_sizes[0] / 32;
  int E = in_sizes[2];
  int G = out_size;
  int NSEG = N * 4;
  int NB = (N + 127) >> 7;

  char* p = (char*)d_ws;
  auto alloc = [&](size_t bytes) {
    char* r = p;
    p += (bytes + 255) & ~(size_t)255;
    return r;
  };
  int permCap = ((N + 63) / 64 + NBUCK) * 64;
  unsigned short* h_bf = (unsigned short*)alloc((size_t)N * 128 * 2);
  unsigned short* h2_bf = (unsigned short*)alloc((size_t)N * 128 * 2);
  unsigned short* Btr = (unsigned short*)alloc((size_t)2 * 128 * 640 * 2);
  unsigned short* Btm = (unsigned short*)alloc((size_t)2 * 11 * 128 * 256 * 2);
  float* inv = (float*)alloc((size_t)NSEG * 4);
  int* cnt = (int*)alloc((size_t)NSEG * 4);
  int* seg_start = (int*)alloc((size_t)NSEG * 4);
  int* csr = (int*)alloc((size_t)E * 4);
  uint2* ebuf = (uint2*)alloc((size_t)E * 8);
  int* deg = (int*)alloc((size_t)N * 4);
  int* bucket = (int*)alloc((size_t)N * 4);
  int* perm = (int*)alloc((size_t)permCap * 4);
  int* boff = (int*)alloc(516 * 4);
  int* bcur = (int*)alloc(512 * 4);
  size_t zeroBytes = 8192 + (size_t)G * 128 * 4;
  char* zb = alloc(zeroBytes);
  int* bhist = (int*)zb;
  int* hist = (int*)(zb + 4096);
  int* fill = (int*)(zb + 4224);
  int* done = (int*)(zb + 4352);
  float* g = (float*)(zb + 8192);

  (void)hipMemsetAsync(zb, 0, zeroBytes, stream);

  const int* src = ei;
  const int* dst = ei + E;

  int sblocks = (E + 4095) / 4096;
  coarse_count_scan<<<sblocks, 512, 0, stream>>>(dst, bhist, boff, bcur, done, perm, permCap,
                                                 NB, E, sblocks);
  coarse_scatter<<<sblocks, 512, 0, stream>>>(src, dst, ea, bcur, ebuf, E);
  fine_place<<<NB, 512, 0, stream>>>(ebuf, boff, cnt, seg_start, inv, deg, bucket, hist, csr,
                                     NSEG);
  build_perm<<<(N + 255) / 256, 256, 0, stream>>>(bucket, hist, fill, perm, N);

  int nbE = (N + 63) / 64;
  int convBlocks = (2 * 128 * 640 + 2 * 11 * 128 * 256 + 255) / 256;
  embed_conv<<<nbE + convBlocks, 256, 0, stream>>>(x, embW, embB, Wrel, Wroot, Wl, Wr, Btr,
                                                   Btm, h_bf, N, nbE);

  int mfblocks = permCap / 64;
  for (int blk = 0; blk < 2; blk++) {
    rgcn_fused<<<mfblocks, 256, 0, stream>>>(h_bf, csr, seg_start, cnt, inv, perm,
                                             Btr + (size_t)blk * 81920, rb + blk * 128,
                                             h2_bf);
    mf_fused<<<mfblocks, 256, 0, stream>>>(h2_bf, csr, seg_start, deg, perm, hist,
                                           Btm + (size_t)blk * 11 * 128 * 256,
                                           bl + (size_t)blk * 11 * 128, h_bf,
                                           (blk == 0) ? 1 : 0);
  }
  pool2<<<G * POOL_CHUNKS, 128, 0, stream>>>(h_bf, batch, g, N, G);
  head_kernel<<<G, 128, 0, stream>>>(g, l1W, l1b, l2W, l2b, out);
}